// Round 1
// baseline (436.449 us; speedup 1.0000x reference)
//
#include <hip/hip_runtime.h>
#include <math.h>

#define VOCAB 100000
#define TOPK  20
#define EMB   300
#define NTOK  (64*256)
#define RB    32   // vocab rows per block in score kernel

// ---------------------------------------------------------------------------
// Kernel 1: s[v] = sum_e tanh( emb[v,:] . a[:,e] ) * b[e]   for v in [0,VOCAB)
// Block: 256 threads = 8 tr-groups x 32 te-lanes. Per-thread tile: 4 rows x
// (4 + 4 + 4) cols  (col groups at e0, e0+128, e0+256; third masked te<11).
// emb rows staged row-major in LDS (linear writes = conflict-free; reads are
// ds_read_b128 broadcast per tr-group). 'a' is read from global (L2-resident,
// 360 KB, ~1.1 GB total traffic across all blocks).
// ---------------------------------------------------------------------------
__global__ __launch_bounds__(256) void score_kernel(
    const float* __restrict__ emb, const float* __restrict__ A,
    const float* __restrict__ B, float* __restrict__ S)
{
    __shared__ __align__(16) float embS[RB * EMB];   // 38.4 KB
    const int t  = threadIdx.x;
    const int v0 = blockIdx.x * RB;                  // VOCAB = 3125*RB exactly

    const float* gsrc = emb + (size_t)v0 * EMB;
    for (int idx = t; idx < RB * EMB; idx += 256)
        embS[idx] = gsrc[idx];
    __syncthreads();

    const int tr = t >> 5;          // 0..7
    const int te = t & 31;          // 0..31
    const int r0 = tr * 4;
    const int e0 = te * 4;
    const bool tail = (te < 11);    // cols 256..299 = 11 float4 groups

    float4 acc0[4], acc1[4], acc2[4];
#pragma unroll
    for (int rr = 0; rr < 4; ++rr) {
        acc0[rr] = make_float4(0.f, 0.f, 0.f, 0.f);
        acc1[rr] = make_float4(0.f, 0.f, 0.f, 0.f);
        acc2[rr] = make_float4(0.f, 0.f, 0.f, 0.f);
    }

    for (int d = 0; d < EMB; d += 4) {
        float4 ev[4];
#pragma unroll
        for (int rr = 0; rr < 4; ++rr)
            ev[rr] = *(const float4*)&embS[(r0 + rr) * EMB + d];
#pragma unroll
        for (int dd = 0; dd < 4; ++dd) {
            const float* arow = A + (d + dd) * EMB;
            float4 a0 = *(const float4*)(arow + e0);
            float4 a1 = *(const float4*)(arow + 128 + e0);
            float4 a2 = tail ? *(const float4*)(arow + 256 + e0)
                             : make_float4(0.f, 0.f, 0.f, 0.f);
#pragma unroll
            for (int rr = 0; rr < 4; ++rr) {
                const float ew = (dd == 0) ? ev[rr].x :
                                 (dd == 1) ? ev[rr].y :
                                 (dd == 2) ? ev[rr].z : ev[rr].w;
                acc0[rr].x = fmaf(ew, a0.x, acc0[rr].x);
                acc0[rr].y = fmaf(ew, a0.y, acc0[rr].y);
                acc0[rr].z = fmaf(ew, a0.z, acc0[rr].z);
                acc0[rr].w = fmaf(ew, a0.w, acc0[rr].w);
                acc1[rr].x = fmaf(ew, a1.x, acc1[rr].x);
                acc1[rr].y = fmaf(ew, a1.y, acc1[rr].y);
                acc1[rr].z = fmaf(ew, a1.z, acc1[rr].z);
                acc1[rr].w = fmaf(ew, a1.w, acc1[rr].w);
                acc2[rr].x = fmaf(ew, a2.x, acc2[rr].x);
                acc2[rr].y = fmaf(ew, a2.y, acc2[rr].y);
                acc2[rr].z = fmaf(ew, a2.z, acc2[rr].z);
                acc2[rr].w = fmaf(ew, a2.w, acc2[rr].w);
            }
        }
    }

    // epilogue: partial[r] = sum over this thread's cols of tanh(dot)*b[e]
    float4 b0 = *(const float4*)(B + e0);
    float4 b1 = *(const float4*)(B + 128 + e0);
    float4 b2 = tail ? *(const float4*)(B + 256 + e0)
                     : make_float4(0.f, 0.f, 0.f, 0.f);

    float part[4];
#pragma unroll
    for (int rr = 0; rr < 4; ++rr) {
        part[rr] = tanhf(acc0[rr].x) * b0.x + tanhf(acc0[rr].y) * b0.y
                 + tanhf(acc0[rr].z) * b0.z + tanhf(acc0[rr].w) * b0.w
                 + tanhf(acc1[rr].x) * b1.x + tanhf(acc1[rr].y) * b1.y
                 + tanhf(acc1[rr].z) * b1.z + tanhf(acc1[rr].w) * b1.w
                 + tanhf(acc2[rr].x) * b2.x + tanhf(acc2[rr].y) * b2.y
                 + tanhf(acc2[rr].z) * b2.z + tanhf(acc2[rr].w) * b2.w;
    }

    // reduce across the 32 te-lanes (stays within each 32-lane half of wave64)
#pragma unroll
    for (int m = 16; m >= 1; m >>= 1) {
#pragma unroll
        for (int rr = 0; rr < 4; ++rr)
            part[rr] += __shfl_xor(part[rr], m);
    }
    if (te == 0) {
#pragma unroll
        for (int rr = 0; rr < 4; ++rr)
            S[v0 + r0 + rr] = part[rr];
    }
}

// ---------------------------------------------------------------------------
// Kernel 2: per token: gather 20 neighbor scores, softmax, weighted sum of
// 20 emb rows. One wave64 per token; 4 tokens per 256-thread block.
// ---------------------------------------------------------------------------
__global__ __launch_bounds__(256) void attend_kernel(
    const int* __restrict__ text, const int* __restrict__ neighbors,
    const float* __restrict__ emb, const float* __restrict__ S,
    float* __restrict__ out)
{
    const int lane = threadIdx.x & 63;
    const int wv   = threadIdx.x >> 6;
    const int tok  = blockIdx.x * 4 + wv;   // NTOK = 4096*4 exactly

    const int tid = text[tok];

    int   nbk = 0;
    float sc  = -1e30f;
    if (lane < TOPK) {
        nbk = neighbors[tid * TOPK + lane];
        sc  = S[nbk];
    }

    // max over the 20 scores (xor masks {16..1} stay within 32-lane halves;
    // lower half holds the true values, upper half unused garbage)
    float mx = sc;
#pragma unroll
    for (int m = 16; m >= 1; m >>= 1)
        mx = fmaxf(mx, __shfl_xor(mx, m));

    float ex = (lane < TOPK) ? expf(sc - mx) : 0.f;
    float sum = ex;
#pragma unroll
    for (int m = 16; m >= 1; m >>= 1)
        sum += __shfl_xor(sum, m);
    float att = ex / sum;   // valid in lanes 0..19 (lower half); others unused

    // weighted sum of neighbor embedding rows
    float acc0 = 0.f, acc1 = 0.f, acc2 = 0.f, acc3 = 0.f, acc4 = 0.f;
    const bool has5 = (lane < EMB - 256);   // lane < 44
#pragma unroll 4
    for (int k = 0; k < TOPK; ++k) {
        const float w  = __shfl(att, k);
        const int   id = __shfl(nbk, k);
        const float* row = emb + (size_t)id * EMB;
        acc0 = fmaf(w, row[lane      ], acc0);
        acc1 = fmaf(w, row[lane +  64], acc1);
        acc2 = fmaf(w, row[lane + 128], acc2);
        acc3 = fmaf(w, row[lane + 192], acc3);
        if (has5) acc4 = fmaf(w, row[lane + 256], acc4);
    }

    float* orow = out + (size_t)tok * EMB;
    orow[lane      ] = acc0;
    orow[lane +  64] = acc1;
    orow[lane + 128] = acc2;
    orow[lane + 192] = acc3;
    if (has5) orow[lane + 256] = acc4;
}

extern "C" void kernel_launch(void* const* d_in, const int* in_sizes, int n_in,
                              void* d_out, int out_size, void* d_ws, size_t ws_size,
                              hipStream_t stream) {
    const int*   text      = (const int*)d_in[0];
    const int*   neighbors = (const int*)d_in[1];
    const float* emb       = (const float*)d_in[2];
    const float* A         = (const float*)d_in[3];
    const float* B         = (const float*)d_in[4];
    float*       out       = (float*)d_out;
    float*       S         = (float*)d_ws;      // VOCAB floats = 400 KB

    score_kernel<<<VOCAB / RB, 256, 0, stream>>>(emb, A, B, S);
    attend_kernel<<<NTOK / 4, 256, 0, stream>>>(text, neighbors, emb, S, out);
}

// Round 2
// 381.811 us; speedup vs baseline: 1.1431x; 1.1431x over previous
//
#include <hip/hip_runtime.h>
#include <math.h>

#define VOCAB 100000
#define TOPK  20
#define EMB   300
#define NTOK  (64*256)
#define RB    32   // vocab rows per block in score kernel
#define DT    20   // K-dim (d) tile

// ---------------------------------------------------------------------------
// Kernel 1: s[v] = sum_e tanh( emb[v,:] . a[:,e] ) * b[e]
// Block: 256 threads = 8 tr-groups x 32 te-lanes. C-tile: 32 rows x 320 cols
// (cols 300..319 are zero-padded in LDS so the te mapping is uniform:
// 5 float2 groups per lane at e = g*64 + te*2).
// Both operands staged in LDS per K-tile: As[DT][320] (25.6 KB, shared by all
// 8 waves -> A global traffic 1.1 GB total instead of 11.5 GB), Es[RB][DT].
// ---------------------------------------------------------------------------
__global__ __launch_bounds__(256, 5) void score_kernel(
    const float* __restrict__ emb, const float* __restrict__ A,
    const float* __restrict__ B, float* __restrict__ S)
{
    __shared__ __align__(16) float As[DT][320];   // 25.6 KB
    __shared__ __align__(16) float Es[RB][DT];    // 2.56 KB
    const int t  = threadIdx.x;
    const int v0 = blockIdx.x * RB;               // VOCAB = 3125*RB exactly

    // zero the A pad (cols 300..319) once; never overwritten by staging
    for (int i = t; i < DT * 20; i += 256) {
        int r = i / 20, c = i - r * 20;
        As[r][300 + c] = 0.f;
    }

    const int tr = t >> 5;          // 0..7
    const int te = t & 31;          // 0..31
    const int r0 = tr * 4;

    float2 acc[4][5];
#pragma unroll
    for (int rr = 0; rr < 4; ++rr)
#pragma unroll
        for (int g = 0; g < 5; ++g)
            acc[rr][g] = make_float2(0.f, 0.f);

    for (int d0 = 0; d0 < EMB; d0 += DT) {
        // stage A tile: DT rows x 300 cols, as 75 float4 per row
        for (int i = t; i < DT * 75; i += 256) {
            int r = i / 75, c4 = i - r * 75;
            *(float4*)&As[r][c4 * 4] =
                *(const float4*)&A[(size_t)(d0 + r) * EMB + c4 * 4];
        }
        // stage emb tile: Es[r][c] = emb[v0+r][d0+c]
        for (int i = t; i < RB * DT; i += 256) {
            int r = i / DT, c = i - r * DT;
            Es[r][c] = emb[(size_t)(v0 + r) * EMB + d0 + c];
        }
        __syncthreads();

        for (int d = 0; d < DT; d += 4) {
            float4 ev[4];
#pragma unroll
            for (int rr = 0; rr < 4; ++rr)
                ev[rr] = *(const float4*)&Es[r0 + rr][d];
#pragma unroll
            for (int dd = 0; dd < 4; ++dd) {
#pragma unroll
                for (int g = 0; g < 5; ++g) {
                    float2 av = *(const float2*)&As[d + dd][g * 64 + te * 2];
#pragma unroll
                    for (int rr = 0; rr < 4; ++rr) {
                        const float ew = (dd == 0) ? ev[rr].x :
                                         (dd == 1) ? ev[rr].y :
                                         (dd == 2) ? ev[rr].z : ev[rr].w;
                        acc[rr][g].x = fmaf(ew, av.x, acc[rr][g].x);
                        acc[rr][g].y = fmaf(ew, av.y, acc[rr][g].y);
                    }
                }
            }
        }
        __syncthreads();
    }

    // epilogue: part[rr] = sum over this lane's 10 cols of tanh(dot)*b[e]
    float2 bv[5];
#pragma unroll
    for (int g = 0; g < 5; ++g) {
        const int e = g * 64 + te * 2;
        bv[g].x = (e     < EMB) ? B[e]     : 0.f;
        bv[g].y = (e + 1 < EMB) ? B[e + 1] : 0.f;
    }

    float part[4];
#pragma unroll
    for (int rr = 0; rr < 4; ++rr) {
        float p = 0.f;
#pragma unroll
        for (int g = 0; g < 5; ++g) {
            p += tanhf(acc[rr][g].x) * bv[g].x;
            p += tanhf(acc[rr][g].y) * bv[g].y;
        }
        part[rr] = p;
    }

    // reduce across the 32 te-lanes (xor masks stay within 32-lane halves)
#pragma unroll
    for (int m = 16; m >= 1; m >>= 1) {
#pragma unroll
        for (int rr = 0; rr < 4; ++rr)
            part[rr] += __shfl_xor(part[rr], m);
    }
    if (te == 0) {
#pragma unroll
        for (int rr = 0; rr < 4; ++rr)
            S[v0 + r0 + rr] = part[rr];
    }
}

// ---------------------------------------------------------------------------
// Kernel 2: per token: gather 20 neighbor scores, softmax, weighted sum of
// 20 emb rows. One wave64 per token; 4 tokens per 256-thread block.
// ---------------------------------------------------------------------------
__global__ __launch_bounds__(256) void attend_kernel(
    const int* __restrict__ text, const int* __restrict__ neighbors,
    const float* __restrict__ emb, const float* __restrict__ S,
    float* __restrict__ out)
{
    const int lane = threadIdx.x & 63;
    const int wv   = threadIdx.x >> 6;
    const int tok  = blockIdx.x * 4 + wv;   // NTOK = 4096*4 exactly

    const int tid = text[tok];

    int   nbk = 0;
    float sc  = -1e30f;
    if (lane < TOPK) {
        nbk = neighbors[tid * TOPK + lane];
        sc  = S[nbk];
    }

    float mx = sc;
#pragma unroll
    for (int m = 16; m >= 1; m >>= 1)
        mx = fmaxf(mx, __shfl_xor(mx, m));

    float ex = (lane < TOPK) ? expf(sc - mx) : 0.f;
    float sum = ex;
#pragma unroll
    for (int m = 16; m >= 1; m >>= 1)
        sum += __shfl_xor(sum, m);
    float att = ex / sum;

    float acc0 = 0.f, acc1 = 0.f, acc2 = 0.f, acc3 = 0.f, acc4 = 0.f;
    const bool has5 = (lane < EMB - 256);   // lane < 44
#pragma unroll 4
    for (int k = 0; k < TOPK; ++k) {
        const float w  = __shfl(att, k);
        const int   id = __shfl(nbk, k);
        const float* row = emb + (size_t)id * EMB;
        acc0 = fmaf(w, row[lane      ], acc0);
        acc1 = fmaf(w, row[lane +  64], acc1);
        acc2 = fmaf(w, row[lane + 128], acc2);
        acc3 = fmaf(w, row[lane + 192], acc3);
        if (has5) acc4 = fmaf(w, row[lane + 256], acc4);
    }

    float* orow = out + (size_t)tok * EMB;
    orow[lane      ] = acc0;
    orow[lane +  64] = acc1;
    orow[lane + 128] = acc2;
    orow[lane + 192] = acc3;
    if (has5) orow[lane + 256] = acc4;
}

extern "C" void kernel_launch(void* const* d_in, const int* in_sizes, int n_in,
                              void* d_out, int out_size, void* d_ws, size_t ws_size,
                              hipStream_t stream) {
    const int*   text      = (const int*)d_in[0];
    const int*   neighbors = (const int*)d_in[1];
    const float* emb       = (const float*)d_in[2];
    const float* A         = (const float*)d_in[3];
    const float* B         = (const float*)d_in[4];
    float*       out       = (float*)d_out;
    float*       S         = (float*)d_ws;      // VOCAB floats = 400 KB

    score_kernel<<<VOCAB / RB, 256, 0, stream>>>(emb, A, B, S);
    attend_kernel<<<NTOK / 4, 256, 0, stream>>>(text, neighbors, emb, S, out);
}

// Round 3
// 228.924 us; speedup vs baseline: 1.9065x; 1.6678x over previous
//
#include <hip/hip_runtime.h>
#include <hip/hip_bf16.h>
#include <math.h>

#define VOCAB 100000
#define TOPK  20
#define EMB   300
#define NTOK  (64*256)
#define NB    1563          // ceil(VOCAB/64)

typedef __attribute__((ext_vector_type(8))) short short8;   // 8 bf16 = 4 VGPR
typedef __attribute__((ext_vector_type(4))) float f32x4;

static __device__ inline short f2bf(float f) {
    __hip_bfloat16 h = __float2bfloat16(f);
    short s; __builtin_memcpy(&s, &h, 2);
    return s;
}

// ---------------------------------------------------------------------------
// prep: aT_hi[e][d] = bf16(a[d][e]), aT_lo[e][d] = bf16(a[d][e] - hi), both
// zero-padded to 320x320. Transposed layout makes the MFMA B-fragment
// (8 consecutive k per lane) a single 16B load.
// ---------------------------------------------------------------------------
__global__ void prep_kernel(const float* __restrict__ A,
                            short* __restrict__ aT_hi, short* __restrict__ aT_lo)
{
    const int e = blockIdx.x;                 // 0..319
    for (int d = threadIdx.x; d < 320; d += 256) {
        float f = (e < EMB && d < EMB) ? A[(size_t)d * EMB + e] : 0.f;
        __hip_bfloat16 h = __float2bfloat16(f);
        short sh; __builtin_memcpy(&sh, &h, 2);
        float fh = __bfloat162float(h);
        short sl = f2bf(f - fh);
        aT_hi[e * 320 + d] = sh;
        aT_lo[e * 320 + d] = sl;
    }
}

// ---------------------------------------------------------------------------
// score: s[v] = sum_e tanh( emb[v,:] . a[:,e] ) * b[e]  via bf16 MFMA.
// Block = 64 v-rows x 320 e-cols, K=320 (10 k-steps of 32).
// 4 waves; wave w owns n-tiles w*5..w*5+4 (5 n x 4 m = 20 16x16 tiles).
// A-frag: swizzled LDS (EsS, 16B chunks, chunk ^= row&7 -> conflict-free).
// B-frag: direct global 16B loads from aT (L2-resident, hi+lo compensated).
// ---------------------------------------------------------------------------
__global__ __launch_bounds__(256) void score_kernel(
    const float* __restrict__ emb, const short* __restrict__ aT_hi,
    const short* __restrict__ aT_lo, const float* __restrict__ B,
    float* __restrict__ S)
{
    __shared__ short8 EsS[64 * 40];           // 40960 B exactly -> 4 blocks/CU
    const int t  = threadIdx.x;
    const int v0 = blockIdx.x * 64;

    // stage emb tile -> bf16 LDS, chunk-XOR swizzle (write side)
    for (int i = t; i < 64 * 40; i += 256) {
        const int row = i / 40, cc = i - row * 40;
        const int v = v0 + row;
        short8 val;
#pragma unroll
        for (int e = 0; e < 8; ++e) {
            const int col = cc * 8 + e;
            float f = (v < VOCAB && col < EMB) ? emb[(size_t)v * EMB + col] : 0.f;
            val[e] = f2bf(f);
        }
        EsS[row * 40 + (cc ^ (row & 7))] = val;
    }
    __syncthreads();

    const int lid = t & 63;
    const int w   = t >> 6;        // wave 0..3
    const int lm  = lid & 15;      // A-row / B-col selector
    const int lk  = lid >> 4;      // k-subgroup 0..3

    f32x4 acc[4][5];
#pragma unroll
    for (int mt = 0; mt < 4; ++mt)
#pragma unroll
        for (int g = 0; g < 5; ++g)
            acc[mt][g] = (f32x4){0.f, 0.f, 0.f, 0.f};

    const short8* aH = (const short8*)aT_hi;
    const short8* aL = (const short8*)aT_lo;

    for (int ks = 0; ks < 10; ++ks) {
        short8 bh[5], bl[5];
#pragma unroll
        for (int g = 0; g < 5; ++g) {
            const int e   = (w * 5 + g) * 16 + lm;
            const int idx = e * 40 + ks * 4 + lk;
            bh[g] = aH[idx];
            bl[g] = aL[idx];
        }
#pragma unroll
        for (int mt = 0; mt < 4; ++mt) {
            const int rowA = mt * 16 + lm;
            short8 af = EsS[rowA * 40 + ((ks * 4 + lk) ^ (rowA & 7))];
#pragma unroll
            for (int g = 0; g < 5; ++g) {
                acc[mt][g] = __builtin_amdgcn_mfma_f32_16x16x32_bf16(af, bh[g], acc[mt][g], 0, 0, 0);
                acc[mt][g] = __builtin_amdgcn_mfma_f32_16x16x32_bf16(af, bl[g], acc[mt][g], 0, 0, 0);
            }
        }
    }

    // epilogue: part[mt][i] = sum_g tanh(acc)*b[col];  C row = mt*16+lk*4+i, col = (w*5+g)*16+lm
    float bcol[5];
#pragma unroll
    for (int g = 0; g < 5; ++g) {
        const int col = (w * 5 + g) * 16 + lm;
        bcol[g] = (col < EMB) ? B[col] : 0.f;
    }

    float part[4][4];
#pragma unroll
    for (int mt = 0; mt < 4; ++mt)
#pragma unroll
        for (int i = 0; i < 4; ++i) {
            float p = 0.f;
#pragma unroll
            for (int g = 0; g < 5; ++g) {
                float x  = acc[mt][g][i];
                float xc = fminf(fmaxf(x, -15.f), 15.f);
                float e2 = __expf(2.f * xc);
                p += __fdividef(e2 - 1.f, e2 + 1.f) * bcol[g];
            }
            part[mt][i] = p;
        }

    // reduce over the 16 lm-lanes (masks 1,2,4,8 keep lk fixed)
#pragma unroll
    for (int m = 1; m <= 8; m <<= 1)
#pragma unroll
        for (int mt = 0; mt < 4; ++mt)
#pragma unroll
            for (int i = 0; i < 4; ++i)
                part[mt][i] += __shfl_xor(part[mt][i], m);

    __syncthreads();                     // done reading EsS; reuse as reduce buf
    float* Sred4 = (float*)EsS;          // [4 waves][64 rows]
    if (lm == 0) {
#pragma unroll
        for (int mt = 0; mt < 4; ++mt)
#pragma unroll
            for (int i = 0; i < 4; ++i)
                Sred4[w * 64 + mt * 16 + lk * 4 + i] = part[mt][i];
    }
    __syncthreads();
    if (t < 64) {
        float s = Sred4[t] + Sred4[64 + t] + Sred4[128 + t] + Sred4[192 + t];
        if (v0 + t < VOCAB) S[v0 + t] = s;
    }
}

// ---------------------------------------------------------------------------
// attend: per token gather 20 neighbor scores, softmax, weighted emb sum.
// ---------------------------------------------------------------------------
__global__ __launch_bounds__(256) void attend_kernel(
    const int* __restrict__ text, const int* __restrict__ neighbors,
    const float* __restrict__ emb, const float* __restrict__ S,
    float* __restrict__ out)
{
    const int lane = threadIdx.x & 63;
    const int wv   = threadIdx.x >> 6;
    const int tok  = blockIdx.x * 4 + wv;

    const int tid = text[tok];

    int   nbk = 0;
    float sc  = -1e30f;
    if (lane < TOPK) {
        nbk = neighbors[tid * TOPK + lane];
        sc  = S[nbk];
    }

    float mx = sc;
#pragma unroll
    for (int m = 16; m >= 1; m >>= 1)
        mx = fmaxf(mx, __shfl_xor(mx, m));

    float ex = (lane < TOPK) ? expf(sc - mx) : 0.f;
    float sum = ex;
#pragma unroll
    for (int m = 16; m >= 1; m >>= 1)
        sum += __shfl_xor(sum, m);
    float att = ex / sum;

    float acc0 = 0.f, acc1 = 0.f, acc2 = 0.f, acc3 = 0.f, acc4 = 0.f;
    const bool has5 = (lane < EMB - 256);
#pragma unroll 4
    for (int k = 0; k < TOPK; ++k) {
        const float w  = __shfl(att, k);
        const int   id = __shfl(nbk, k);
        const float* row = emb + (size_t)id * EMB;
        acc0 = fmaf(w, row[lane      ], acc0);
        acc1 = fmaf(w, row[lane +  64], acc1);
        acc2 = fmaf(w, row[lane + 128], acc2);
        acc3 = fmaf(w, row[lane + 192], acc3);
        if (has5) acc4 = fmaf(w, row[lane + 256], acc4);
    }

    float* orow = out + (size_t)tok * EMB;
    orow[lane      ] = acc0;
    orow[lane +  64] = acc1;
    orow[lane + 128] = acc2;
    orow[lane + 192] = acc3;
    if (has5) orow[lane + 256] = acc4;
}

extern "C" void kernel_launch(void* const* d_in, const int* in_sizes, int n_in,
                              void* d_out, int out_size, void* d_ws, size_t ws_size,
                              hipStream_t stream) {
    const int*   text      = (const int*)d_in[0];
    const int*   neighbors = (const int*)d_in[1];
    const float* emb       = (const float*)d_in[2];
    const float* A         = (const float*)d_in[3];
    const float* B         = (const float*)d_in[4];
    float*       out       = (float*)d_out;

    char* ws = (char*)d_ws;
    float* S     = (float*)ws;                   // 400,000 B
    short* aT_hi = (short*)(ws + 400000);        // 204,800 B (16B-aligned)
    short* aT_lo = (short*)(ws + 604800);        // 204,800 B

    prep_kernel<<<320, 256, 0, stream>>>(A, aT_hi, aT_lo);
    score_kernel<<<NB, 256, 0, stream>>>(emb, aT_hi, aT_lo, B, S);
    attend_kernel<<<NTOK / 4, 256, 0, stream>>>(text, neighbors, emb, S, out);
}

// Round 5
// 213.129 us; speedup vs baseline: 2.0478x; 1.0741x over previous
//
#include <hip/hip_runtime.h>
#include <hip/hip_bf16.h>
#include <math.h>

#define VOCAB 100000
#define TOPK  20
#define EMB   300
#define NTOK  (64*256)
#define NB    1563          // ceil(VOCAB/64)

typedef __attribute__((ext_vector_type(8))) short short8;   // 8 bf16 = 4 VGPR
typedef __attribute__((ext_vector_type(4))) float f32x4;

static __device__ inline short f2bf(float f) {
    __hip_bfloat16 h = __float2bfloat16(f);
    short s; __builtin_memcpy(&s, &h, 2);
    return s;
}

// ---------------------------------------------------------------------------
// prep: aT[e][d] = bf16(a[d][e]), zero-padded to 320x320. Transposed so the
// MFMA B-fragment (8 consecutive k per lane) is one 16B load.
// ---------------------------------------------------------------------------
__global__ void prep_kernel(const float* __restrict__ A, short* __restrict__ aT)
{
    const int e = blockIdx.x;                 // 0..319
    for (int d = threadIdx.x; d < 320; d += 256) {
        float f = (e < EMB && d < EMB) ? A[(size_t)d * EMB + e] : 0.f;
        aT[e * 320 + d] = f2bf(f);
    }
}

// ---------------------------------------------------------------------------
// score: s[v] = sum_e tanh( emb[v,:] . a[:,e] ) * b[e]  via bf16 MFMA.
// Block = 64 v-rows x 320 e-cols, K=320 (10 k-steps of 32), 512 threads.
// Wave w: mg = w>>2 owns m-tiles {2mg, 2mg+1} (rows mg*32..mg*32+31),
// ng = w&3 owns n-tiles ng*5..ng*5+4.  acc[2][5] = 40 VGPR/lane.
// A-frag: swizzled LDS (16B chunks, chunk ^= row&7 -> 0 bank conflicts, r3).
// B-frag: global 16B loads from L2-resident aT, register double-buffered
// (fully unrolled k-loop so all bh[] indices are compile-time).
// Cross-wave reduce: Sred[ng][row] — waves (mg=0,ng)/(mg=1,ng) write disjoint
// 32-row halves, so every slot is written exactly once (r4 bug: [wave][row]
// layout left half the slots uninitialized).
// ---------------------------------------------------------------------------
__global__ __launch_bounds__(512, 4) void score_kernel(
    const float* __restrict__ emb, const short* __restrict__ aT,
    const float* __restrict__ B, float* __restrict__ S)
{
    __shared__ short8 EsS[64 * 40];           // 40960 B
    const int t  = threadIdx.x;
    const int v0 = blockIdx.x * 64;

    // stage emb tile -> bf16 LDS, chunk-XOR swizzle (write side)
    for (int i = t; i < 64 * 40; i += 512) {
        const int row = i / 40, cc = i - row * 40;
        const int v = v0 + row;
        short8 val;
#pragma unroll
        for (int e = 0; e < 8; ++e) {
            const int col = cc * 8 + e;
            float f = (v < VOCAB && col < EMB) ? emb[(size_t)v * EMB + col] : 0.f;
            val[e] = f2bf(f);
        }
        EsS[row * 40 + (cc ^ (row & 7))] = val;
    }
    __syncthreads();

    const int lid = t & 63;
    const int w   = t >> 6;        // wave 0..7
    const int mg  = w >> 2;        // m-group 0..1
    const int ng  = w & 3;         // n-group 0..3
    const int lm  = lid & 15;      // A-row / B-col selector
    const int lk  = lid >> 4;      // k-subgroup 0..3

    f32x4 acc[2][5];
#pragma unroll
    for (int mt = 0; mt < 2; ++mt)
#pragma unroll
        for (int g = 0; g < 5; ++g)
            acc[mt][g] = (f32x4){0.f, 0.f, 0.f, 0.f};

    const short8* aH = (const short8*)aT;
    // per-lane base index into aT (short8 units): e-col base + lk chunk
    int bidx[5];
#pragma unroll
    for (int g = 0; g < 5; ++g)
        bidx[g] = ((ng * 5 + g) * 16 + lm) * 40 + lk;

    short8 bh[2][5];
#pragma unroll
    for (int g = 0; g < 5; ++g)
        bh[0][g] = aH[bidx[g]];            // prologue: ks=0 chunks

#pragma unroll
    for (int ks = 0; ks < 10; ++ks) {
        const int cur = ks & 1, nxt = cur ^ 1;
        if (ks < 9) {
#pragma unroll
            for (int g = 0; g < 5; ++g)
                bh[nxt][g] = aH[bidx[g] + (ks + 1) * 4];
        }
#pragma unroll
        for (int mt = 0; mt < 2; ++mt) {
            const int rowA = (mg * 2 + mt) * 16 + lm;
            short8 af = EsS[rowA * 40 + ((ks * 4 + lk) ^ (rowA & 7))];
#pragma unroll
            for (int g = 0; g < 5; ++g)
                acc[mt][g] = __builtin_amdgcn_mfma_f32_16x16x32_bf16(
                                 af, bh[cur][g], acc[mt][g], 0, 0, 0);
        }
    }

    // epilogue: part[mt][i] = sum_g tanh(acc)*b[col]
    // C layout: row = (mg*2+mt)*16 + lk*4 + i, col = (ng*5+g)*16 + lm
    float bcol[5];
#pragma unroll
    for (int g = 0; g < 5; ++g) {
        const int col = (ng * 5 + g) * 16 + lm;
        bcol[g] = (col < EMB) ? B[col] : 0.f;
    }

    float part[2][4];
#pragma unroll
    for (int mt = 0; mt < 2; ++mt)
#pragma unroll
        for (int i = 0; i < 4; ++i) {
            float p = 0.f;
#pragma unroll
            for (int g = 0; g < 5; ++g) {
                float x  = acc[mt][g][i];
                float xc = fminf(fmaxf(x, -15.f), 15.f);
                float e2 = __expf(2.f * xc);
                p += __fdividef(e2 - 1.f, e2 + 1.f) * bcol[g];
            }
            part[mt][i] = p;
        }

    // reduce over the 16 lm-lanes (masks 1,2,4,8 keep lk fixed)
#pragma unroll
    for (int m = 1; m <= 8; m <<= 1)
#pragma unroll
        for (int mt = 0; mt < 2; ++mt)
#pragma unroll
            for (int i = 0; i < 4; ++i)
                part[mt][i] += __shfl_xor(part[mt][i], m);

    __syncthreads();                     // done reading EsS; reuse as reduce buf
    float* Sred = (float*)EsS;           // [4 ng-planes][64 rows]
    if (lm == 0) {
#pragma unroll
        for (int mt = 0; mt < 2; ++mt)
#pragma unroll
            for (int i = 0; i < 4; ++i)
                Sred[ng * 64 + mg * 32 + mt * 16 + lk * 4 + i] = part[mt][i];
    }
    __syncthreads();
    if (t < 64) {
        float s = Sred[t] + Sred[64 + t] + Sred[128 + t] + Sred[192 + t];
        if (v0 + t < VOCAB) S[v0 + t] = s;
    }
}

// ---------------------------------------------------------------------------
// attend: per token gather 20 neighbor scores, softmax, weighted emb sum.
// ---------------------------------------------------------------------------
__global__ __launch_bounds__(256) void attend_kernel(
    const int* __restrict__ text, const int* __restrict__ neighbors,
    const float* __restrict__ emb, const float* __restrict__ S,
    float* __restrict__ out)
{
    const int lane = threadIdx.x & 63;
    const int wv   = threadIdx.x >> 6;
    const int tok  = blockIdx.x * 4 + wv;

    const int tid = text[tok];

    int   nbk = 0;
    float sc  = -1e30f;
    if (lane < TOPK) {
        nbk = neighbors[tid * TOPK + lane];
        sc  = S[nbk];
    }

    float mx = sc;
#pragma unroll
    for (int m = 16; m >= 1; m >>= 1)
        mx = fmaxf(mx, __shfl_xor(mx, m));

    float ex = (lane < TOPK) ? expf(sc - mx) : 0.f;
    float sum = ex;
#pragma unroll
    for (int m = 16; m >= 1; m >>= 1)
        sum += __shfl_xor(sum, m);
    float att = ex / sum;

    float acc0 = 0.f, acc1 = 0.f, acc2 = 0.f, acc3 = 0.f, acc4 = 0.f;
    const bool has5 = (lane < EMB - 256);
#pragma unroll 4
    for (int k = 0; k < TOPK; ++k) {
        const float w  = __shfl(att, k);
        const int   id = __shfl(nbk, k);
        const float* row = emb + (size_t)id * EMB;
        acc0 = fmaf(w, row[lane      ], acc0);
        acc1 = fmaf(w, row[lane +  64], acc1);
        acc2 = fmaf(w, row[lane + 128], acc2);
        acc3 = fmaf(w, row[lane + 192], acc3);
        if (has5) acc4 = fmaf(w, row[lane + 256], acc4);
    }

    float* orow = out + (size_t)tok * EMB;
    orow[lane      ] = acc0;
    orow[lane +  64] = acc1;
    orow[lane + 128] = acc2;
    orow[lane + 192] = acc3;
    if (has5) orow[lane + 256] = acc4;
}

extern "C" void kernel_launch(void* const* d_in, const int* in_sizes, int n_in,
                              void* d_out, int out_size, void* d_ws, size_t ws_size,
                              hipStream_t stream) {
    const int*   text      = (const int*)d_in[0];
    const int*   neighbors = (const int*)d_in[1];
    const float* emb       = (const float*)d_in[2];
    const float* A         = (const float*)d_in[3];
    const float* B         = (const float*)d_in[4];
    float*       out       = (float*)d_out;

    char* ws = (char*)d_ws;
    float* S  = (float*)ws;                 // 400,000 B
    short* aT = (short*)(ws + 400000);      // 204,800 B (16B-aligned)

    prep_kernel<<<320, 256, 0, stream>>>(A, aT);
    score_kernel<<<NB, 512, 0, stream>>>(emb, aT, B, S);
    attend_kernel<<<NTOK / 4, 256, 0, stream>>>(text, neighbors, emb, S, out);
}

// Round 6
// 133.140 us; speedup vs baseline: 3.2781x; 1.6008x over previous
//
#include <hip/hip_runtime.h>
#include <hip/hip_bf16.h>
#include <math.h>

#define VOCAB 100000
#define TOPK  20
#define EMB   300
#define NTOK  (64*256)
#define NB    1563          // ceil(VOCAB/64)

typedef __attribute__((ext_vector_type(8))) short short8;   // 8 bf16 = 4 VGPR
typedef __attribute__((ext_vector_type(4))) short short4v;  // 8 B
typedef __attribute__((ext_vector_type(4))) float f32x4;

static __device__ inline short f2bf(float f) {
    __hip_bfloat16 h = __float2bfloat16(f);
    short s; __builtin_memcpy(&s, &h, 2);
    return s;
}

// ---------------------------------------------------------------------------
// prep: aT[e][d] = bf16(a[d][e]), zero-padded to 320x320.
// ---------------------------------------------------------------------------
__global__ void prep_kernel(const float* __restrict__ A, short* __restrict__ aT)
{
    const int e = blockIdx.x;                 // 0..319
    for (int d = threadIdx.x; d < 320; d += 256) {
        float f = (e < EMB && d < EMB) ? A[(size_t)d * EMB + e] : 0.f;
        aT[e * 320 + d] = f2bf(f);
    }
}

// B-staging source index (short8 units) for linear LDS slot p at k-step ks:
// col = p>>2, slot = p&3, chunk c = slot ^ ((col>>1)&3)  (involution per col)
static __device__ inline int bsrc_idx(int p, int ks) {
    const int col = p >> 2, slot = p & 3;
    const int c = slot ^ ((col >> 1) & 3);
    return col * 40 + ks * 4 + c;
}

// ---------------------------------------------------------------------------
// score: s[v] = sum_e tanh( emb[v,:] . a[:,e] ) * b[e]  via bf16 MFMA.
// Block = 64 v-rows x 320 e-cols, K=320 (10 k-steps of 32), 512 threads.
// BOTH operands from LDS: A (emb tile, 40 KB, staged once w/ coalesced
// float4 loads) + B (aT k-slice, 20 KB/step, double-buffered, T14 split:
// global loads issued BEFORE the MFMA block, ds_write after -> L2 latency
// hidden under compute; loads can't be sunk past their LDS store).
// 80 KB LDS -> 2 blocks/CU (16 waves). acc[2][5] = 40 VGPR.
// ---------------------------------------------------------------------------
__global__ __launch_bounds__(512, 4) void score_kernel(
    const float* __restrict__ emb, const short* __restrict__ aT,
    const float* __restrict__ B, float* __restrict__ S)
{
    __shared__ short8 EsS[64 * 40];       // A tile, 40960 B
    __shared__ short8 Bs[2][1280];        // B k-slice dbuf, 2 x 20480 B
    const int t  = threadIdx.x;
    const int v0 = blockIdx.x * 64;

    // ---- stage A: 64 rows x 300 cols = 4800 aligned float4 (75 per row)
    {
        const float4* esrc = (const float4*)(emb + (size_t)v0 * EMB);
        for (int p4 = t; p4 < 4800; p4 += 512) {
            const int row = p4 / 75, c4 = p4 - row * 75;
            float4 f = make_float4(0.f, 0.f, 0.f, 0.f);
            if (v0 + row < VOCAB) f = esrc[p4];
            short4v h;
            h.x = f2bf(f.x); h.y = f2bf(f.y); h.z = f2bf(f.z); h.w = f2bf(f.w);
            short* base = (short*)&EsS[row * 40 + ((c4 >> 1) ^ (row & 7))];
            *(short4v*)(base + (c4 & 1) * 4) = h;
        }
        // zero K-pad (cols 300..319): chunk37.half1, chunks 38,39 both halves
        for (int i = t; i < 64 * 5; i += 512) {
            const int row = i / 5, q = i - row * 5;
            const int cc = 37 + ((q + 1) >> 1), half = (q + 1) & 1;
            short* base = (short*)&EsS[row * 40 + (cc ^ (row & 7))];
            *(short4v*)(base + half * 4) = (short4v){0, 0, 0, 0};
        }
    }

    const short8* aH = (const short8*)aT;
    const int sp0 = t, sp1 = t + 512, sp2 = t + 1024;   // sp2 valid if t<256

    // ---- prologue: stage B k-step 0 into Bs[0]
    {
        short8 r0 = aH[bsrc_idx(sp0, 0)];
        short8 r1 = aH[bsrc_idx(sp1, 0)];
        short8 r2 = {};
        if (t < 256) r2 = aH[bsrc_idx(sp2, 0)];
        Bs[0][sp0] = r0; Bs[0][sp1] = r1;
        if (t < 256) Bs[0][sp2] = r2;
    }
    __syncthreads();

    const int lid = t & 63;
    const int w   = t >> 6;        // wave 0..7
    const int mg  = w >> 2;        // m-group 0..1  (rows mg*32..mg*32+31)
    const int ng  = w & 3;         // n-group 0..3  (cols ng*80..ng*80+79)
    const int lm  = lid & 15;
    const int lk  = lid >> 4;

    f32x4 acc[2][5];
#pragma unroll
    for (int mt = 0; mt < 2; ++mt)
#pragma unroll
        for (int g = 0; g < 5; ++g)
            acc[mt][g] = (f32x4){0.f, 0.f, 0.f, 0.f};

    // B-frag LDS read offsets (short8 units): col*4 + (lk ^ ((col>>1)&3))
    int boff[5];
#pragma unroll
    for (int g = 0; g < 5; ++g) {
        const int col = (ng * 5 + g) * 16 + lm;
        boff[g] = col * 4 + (lk ^ ((col >> 1) & 3));
    }

#pragma unroll
    for (int ks = 0; ks < 10; ++ks) {
        const int cur = ks & 1, nb = cur ^ 1;

        // T14: issue next k-step's global loads FIRST
        short8 s0 = {}, s1 = {}, s2 = {};
        if (ks < 9) {
            s0 = aH[bsrc_idx(sp0, ks + 1)];
            s1 = aH[bsrc_idx(sp1, ks + 1)];
            if (t < 256) s2 = aH[bsrc_idx(sp2, ks + 1)];
        }

        // compute ks from LDS (covers the load latency)
        short8 bfrag[5];
#pragma unroll
        for (int g = 0; g < 5; ++g)
            bfrag[g] = Bs[cur][boff[g]];
#pragma unroll
        for (int mt = 0; mt < 2; ++mt) {
            const int rowA = (mg * 2 + mt) * 16 + lm;
            short8 af = EsS[rowA * 40 + ((ks * 4 + lk) ^ (rowA & 7))];
#pragma unroll
            for (int g = 0; g < 5; ++g)
                acc[mt][g] = __builtin_amdgcn_mfma_f32_16x16x32_bf16(
                                 af, bfrag[g], acc[mt][g], 0, 0, 0);
        }

        // write the staged regs to the other buffer, then barrier
        if (ks < 9) {
            Bs[nb][sp0] = s0; Bs[nb][sp1] = s1;
            if (t < 256) Bs[nb][sp2] = s2;
        }
        __syncthreads();
    }

    // epilogue: part[mt][i] = sum_g tanh(acc)*b[col]
    // C layout: row = (mg*2+mt)*16 + lk*4 + i, col = (ng*5+g)*16 + lm
    float bcol[5];
#pragma unroll
    for (int g = 0; g < 5; ++g) {
        const int col = (ng * 5 + g) * 16 + lm;
        bcol[g] = (col < EMB) ? B[col] : 0.f;
    }

    float part[2][4];
#pragma unroll
    for (int mt = 0; mt < 2; ++mt)
#pragma unroll
        for (int i = 0; i < 4; ++i) {
            float p = 0.f;
#pragma unroll
            for (int g = 0; g < 5; ++g) {
                float x  = acc[mt][g][i];
                float xc = fminf(fmaxf(x, -15.f), 15.f);
                float e2 = __expf(2.f * xc);
                p += __fdividef(e2 - 1.f, e2 + 1.f) * bcol[g];
            }
            part[mt][i] = p;
        }

#pragma unroll
    for (int m = 1; m <= 8; m <<= 1)
#pragma unroll
        for (int mt = 0; mt < 2; ++mt)
#pragma unroll
            for (int i = 0; i < 4; ++i)
                part[mt][i] += __shfl_xor(part[mt][i], m);

    // k-loop's final barrier guarantees all EsS reads done -> reuse as buffer
    float* Sred = (float*)EsS;           // [4 ng-planes][64 rows]
    if (lm == 0) {
#pragma unroll
        for (int mt = 0; mt < 2; ++mt)
#pragma unroll
            for (int i = 0; i < 4; ++i)
                Sred[ng * 64 + mg * 32 + mt * 16 + lk * 4 + i] = part[mt][i];
    }
    __syncthreads();
    if (t < 64) {
        float s = Sred[t] + Sred[64 + t] + Sred[128 + t] + Sred[192 + t];
        if (v0 + t < VOCAB) S[v0 + t] = s;
    }
}

// ---------------------------------------------------------------------------
// attend: per token gather 20 neighbor scores, softmax, weighted emb sum.
// ---------------------------------------------------------------------------
__global__ __launch_bounds__(256) void attend_kernel(
    const int* __restrict__ text, const int* __restrict__ neighbors,
    const float* __restrict__ emb, const float* __restrict__ S,
    float* __restrict__ out)
{
    const int lane = threadIdx.x & 63;
    const int wv   = threadIdx.x >> 6;
    const int tok  = blockIdx.x * 4 + wv;

    const int tid = text[tok];

    int   nbk = 0;
    float sc  = -1e30f;
    if (lane < TOPK) {
        nbk = neighbors[tid * TOPK + lane];
        sc  = S[nbk];
    }

    float mx = sc;
#pragma unroll
    for (int m = 16; m >= 1; m >>= 1)
        mx = fmaxf(mx, __shfl_xor(mx, m));

    float ex = (lane < TOPK) ? expf(sc - mx) : 0.f;
    float sum = ex;
#pragma unroll
    for (int m = 16; m >= 1; m >>= 1)
        sum += __shfl_xor(sum, m);
    float att = ex / sum;

    float acc0 = 0.f, acc1 = 0.f, acc2 = 0.f, acc3 = 0.f, acc4 = 0.f;
    const bool has5 = (lane < EMB - 256);
#pragma unroll 4
    for (int k = 0; k < TOPK; ++k) {
        const float w  = __shfl(att, k);
        const int   id = __shfl(nbk, k);
        const float* row = emb + (size_t)id * EMB;
        acc0 = fmaf(w, row[lane      ], acc0);
        acc1 = fmaf(w, row[lane +  64], acc1);
        acc2 = fmaf(w, row[lane + 128], acc2);
        acc3 = fmaf(w, row[lane + 192], acc3);
        if (has5) acc4 = fmaf(w, row[lane + 256], acc4);
    }

    float* orow = out + (size_t)tok * EMB;
    orow[lane      ] = acc0;
    orow[lane +  64] = acc1;
    orow[lane + 128] = acc2;
    orow[lane + 192] = acc3;
    if (has5) orow[lane + 256] = acc4;
}

extern "C" void kernel_launch(void* const* d_in, const int* in_sizes, int n_in,
                              void* d_out, int out_size, void* d_ws, size_t ws_size,
                              hipStream_t stream) {
    const int*   text      = (const int*)d_in[0];
    const int*   neighbors = (const int*)d_in[1];
    const float* emb       = (const float*)d_in[2];
    const float* A         = (const float*)d_in[3];
    const float* B         = (const float*)d_in[4];
    float*       out       = (float*)d_out;

    char* ws = (char*)d_ws;
    float* S  = (float*)ws;                 // 400,000 B
    short* aT = (short*)(ws + 400000);      // 204,800 B (16B-aligned)

    prep_kernel<<<320, 256, 0, stream>>>(A, aT);
    score_kernel<<<NB, 512, 0, stream>>>(emb, aT, B, S);
    attend_kernel<<<NTOK / 4, 256, 0, stream>>>(text, neighbors, emb, S, out);
}

// Round 7
// 128.954 us; speedup vs baseline: 3.3845x; 1.0325x over previous
//
#include <hip/hip_runtime.h>
#include <hip/hip_bf16.h>
#include <math.h>

#define VOCAB 100000
#define TOPK  20
#define EMB   300
#define NTOK  (64*256)
#define NB    1563          // ceil(VOCAB/64) v-tiles
#define NSLICE 128          // v-tile slices (blocks per e-half)

typedef __attribute__((ext_vector_type(8))) short short8;   // 8 bf16 = 4 VGPR
typedef __attribute__((ext_vector_type(4))) short short4v;  // 8 B
typedef __attribute__((ext_vector_type(4))) float f32x4;

static __device__ inline short f2bf(float f) {
    __hip_bfloat16 h = __float2bfloat16(f);
    short s; __builtin_memcpy(&s, &h, 2);
    return s;
}

// ---------------------------------------------------------------------------
// prep: aT[e][d] = bf16(a[d][e]), zero-padded to 320x320.
// ---------------------------------------------------------------------------
__global__ void prep_kernel(const float* __restrict__ A, short* __restrict__ aT)
{
    const int e = blockIdx.x;                 // 0..319
    for (int d = threadIdx.x; d < 320; d += 256) {
        float f = (e < EMB && d < EMB) ? A[(size_t)d * EMB + e] : 0.f;
        aT[e * 320 + d] = f2bf(f);
    }
}

// ---------------------------------------------------------------------------
// score: s[v] = sum_e tanh( emb[v,:] . a[:,e] ) * b[e]  via bf16 MFMA.
// Persistent: 256 blocks (1/CU), block = (e-half eh, v-slice). B-half
// (160 cols x 320 k, 102.4 KB) staged in LDS ONCE per block; then ~12
// v-tiles, each: cvt+write prefetched A regs -> LDS, barrier, 5-step
// k-loop with NO barriers / NO global loads (reg-dbuf'd LDS frags),
// kh-pair combine via LDS scratch, tanh epilogue, partial-S store.
// Waves: 2mg x 2ng x 2kh; wave tile 32 rows x 80 cols, k-half of 160.
// All LDS frag reads swizzled by (lm&7) -> conflict-free.
// ---------------------------------------------------------------------------
__global__ __launch_bounds__(512, 2) void score_kernel(
    const float* __restrict__ emb, const short* __restrict__ aT,
    const float* __restrict__ B, float* __restrict__ S0, float* __restrict__ S1)
{
    __shared__ short8 BsS[160 * 40];     // 102400 B : B-half, block-stationary
    __shared__ short8 EsS[64 * 40];      // 40960 B  : A tile (scratch overlay)
    __shared__ float  Sred[128];         // 512 B

    const int t     = threadIdx.x;
    const int eh    = blockIdx.x >> 7;   // 0..1 e-half
    const int slice = blockIdx.x & 127;  // 0..127

    // ---- one-time: stage B-half. 6400 chunks, linear+XOR layout.
#pragma unroll
    for (int j = 0; j < 13; ++j) {
        const int i = t + j * 512;
        if (i < 6400) {
            const int col = i / 40, kc = i - col * 40;
            short8 v = ((const short8*)aT)[(eh * 160 + col) * 40 + kc];
            BsS[col * 40 + (kc ^ (col & 7))] = v;
        }
    }

    const int lid = t & 63;
    const int w   = t >> 6;        // 0..7
    const int kh  = w >> 2;        // k-half 0..1
    const int mg  = (w >> 1) & 1;  // m-pair (rows mg*32..mg*32+31)
    const int ng  = w & 1;         // n-group (cols ng*80..ng*80+79)
    const int lm  = lid & 15;
    const int lk  = lid >> 4;
    const int kh20  = kh * 20;     // k-chunk base
    const int xmask = lm & 7;      // rowA%8 == col%8 == lm%8

    int colb[5], rb[2];
    float bcol[5];
#pragma unroll
    for (int g = 0; g < 5; ++g) {
        const int col = (ng * 5 + g) * 16 + lm;
        colb[g] = col * 40;
        const int e = eh * 160 + col;
        bcol[g] = (e < EMB) ? B[e] : 0.f;
    }
#pragma unroll
    for (int mt = 0; mt < 2; ++mt)
        rb[mt] = (mg * 32 + mt * 16 + lm) * 40;

    const int ntiles = (NB - slice + NSLICE - 1) / NSLICE;
    float4 pf[10];

    // prefetch A for first tile
    {
        const float4* esrc = (const float4*)(emb + (size_t)slice * 64 * EMB);
#pragma unroll
        for (int j = 0; j < 10; ++j) {
            const int p4 = t + j * 512;
            float4 f = make_float4(0.f, 0.f, 0.f, 0.f);
            if (p4 < 4800 && slice * 64 + p4 / 75 < VOCAB) f = esrc[p4];
            pf[j] = f;
        }
    }

    for (int tt = 0; tt < ntiles; ++tt) {
        const int tile = slice + tt * NSLICE;
        const int v0   = tile * 64;

        // ---- cvt + write prefetched A to LDS (swizzled), zero k-pad
#pragma unroll
        for (int j = 0; j < 10; ++j) {
            const int p4 = t + j * 512;
            if (p4 < 4800) {
                const int row = p4 / 75, c4 = p4 - row * 75;
                short4v h;
                h.x = f2bf(pf[j].x); h.y = f2bf(pf[j].y);
                h.z = f2bf(pf[j].z); h.w = f2bf(pf[j].w);
                short* base = (short*)&EsS[row * 40 + ((c4 >> 1) ^ (row & 7))];
                *(short4v*)(base + (c4 & 1) * 4) = h;
            }
        }
        if (t < 320) {   // 64 rows x 5 half-chunks (k 300..319)
            const int row = t / 5, q = t - row * 5;
            const int cc = 37 + ((q + 1) >> 1), half = (q + 1) & 1;
            short* base = (short*)&EsS[row * 40 + (cc ^ (row & 7))];
            *(short4v*)(base + half * 4) = (short4v){0, 0, 0, 0};
        }

        // ---- prefetch A for next tile (consumed next iteration)
        if (tt + 1 < ntiles) {
            const int tn = tile + NSLICE;
            const float4* esrc = (const float4*)(emb + (size_t)tn * 64 * EMB);
#pragma unroll
            for (int j = 0; j < 10; ++j) {
                const int p4 = t + j * 512;
                float4 f = make_float4(0.f, 0.f, 0.f, 0.f);
                if (p4 < 4800 && tn * 64 + p4 / 75 < VOCAB) f = esrc[p4];
                pf[j] = f;
            }
        }
        __syncthreads();                          // B1: A (and B on tt=0) ready

        // ---- k-loop: 5 steps, no barriers, reg-dbuf'd frags
        f32x4 acc[2][5];
#pragma unroll
        for (int mt = 0; mt < 2; ++mt)
#pragma unroll
            for (int g = 0; g < 5; ++g)
                acc[mt][g] = (f32x4){0.f, 0.f, 0.f, 0.f};

        short8 bfr[2][5], afr[2][2];
        {
            const int kx = (kh20 + lk) ^ xmask;
#pragma unroll
            for (int g = 0; g < 5; ++g) bfr[0][g] = BsS[colb[g] + kx];
#pragma unroll
            for (int mt = 0; mt < 2; ++mt) afr[0][mt] = EsS[rb[mt] + kx];
        }
#pragma unroll
        for (int ks = 0; ks < 5; ++ks) {
            const int cur = ks & 1, nx = cur ^ 1;
            if (ks < 4) {
                const int kx = (kh20 + (ks + 1) * 4 + lk) ^ xmask;
#pragma unroll
                for (int g = 0; g < 5; ++g) bfr[nx][g] = BsS[colb[g] + kx];
#pragma unroll
                for (int mt = 0; mt < 2; ++mt) afr[nx][mt] = EsS[rb[mt] + kx];
            }
#pragma unroll
            for (int mt = 0; mt < 2; ++mt)
#pragma unroll
                for (int g = 0; g < 5; ++g)
                    acc[mt][g] = __builtin_amdgcn_mfma_f32_16x16x32_bf16(
                                     afr[cur][mt], bfr[cur][g], acc[mt][g], 0, 0, 0);
        }
        __syncthreads();                          // B2: EsS reads done

        // ---- kh-pair combine (pre-tanh!) via scratch overlaying EsS
        float* scratchF = (float*)EsS;            // [20 q][4 cell][64 lane]
        const int cell = mg * 2 + ng;
        if (kh == 1) {
#pragma unroll
            for (int mt = 0; mt < 2; ++mt)
#pragma unroll
                for (int g = 0; g < 5; ++g)
#pragma unroll
                    for (int i = 0; i < 4; ++i) {
                        const int q = (mt * 5 + g) * 4 + i;
                        scratchF[(q * 4 + cell) * 64 + lid] = acc[mt][g][i];
                    }
        }
        __syncthreads();                          // B3: partials ready

        if (kh == 0) {
            float part[2][4];
#pragma unroll
            for (int mt = 0; mt < 2; ++mt)
#pragma unroll
                for (int i = 0; i < 4; ++i) {
                    float p = 0.f;
#pragma unroll
                    for (int g = 0; g < 5; ++g) {
                        const int q = (mt * 5 + g) * 4 + i;
                        float x  = acc[mt][g][i] + scratchF[(q * 4 + cell) * 64 + lid];
                        float xc = fminf(fmaxf(x, -15.f), 15.f);
                        float e2 = __expf(2.f * xc);
                        p += __fdividef(e2 - 1.f, e2 + 1.f) * bcol[g];
                    }
                    part[mt][i] = p;
                }
#pragma unroll
            for (int m = 1; m <= 8; m <<= 1)
#pragma unroll
                for (int mt = 0; mt < 2; ++mt)
#pragma unroll
                    for (int i = 0; i < 4; ++i)
                        part[mt][i] += __shfl_xor(part[mt][i], m);
            if (lm == 0) {
#pragma unroll
                for (int mt = 0; mt < 2; ++mt)
#pragma unroll
                    for (int i = 0; i < 4; ++i)
                        Sred[ng * 64 + mg * 32 + mt * 16 + lk * 4 + i] = part[mt][i];
            }
        }
        __syncthreads();                          // B4: Sred ready, EsS free

        if (t < 64) {
            const int v = v0 + t;
            if (v < VOCAB) {
                float* Sp = eh ? S1 : S0;
                Sp[v] = Sred[t] + Sred[64 + t];
            }
        }
    }
}

// ---------------------------------------------------------------------------
// attend: per token gather 20 neighbor scores (S0+S1), softmax, weighted sum.
// ---------------------------------------------------------------------------
__global__ __launch_bounds__(256) void attend_kernel(
    const int* __restrict__ text, const int* __restrict__ neighbors,
    const float* __restrict__ emb, const float* __restrict__ S0,
    const float* __restrict__ S1, float* __restrict__ out)
{
    const int lane = threadIdx.x & 63;
    const int wv   = threadIdx.x >> 6;
    const int tok  = blockIdx.x * 4 + wv;

    const int tid = text[tok];

    int   nbk = 0;
    float sc  = -1e30f;
    if (lane < TOPK) {
        nbk = neighbors[tid * TOPK + lane];
        sc  = S0[nbk] + S1[nbk];
    }

    float mx = sc;
#pragma unroll
    for (int m = 16; m >= 1; m >>= 1)
        mx = fmaxf(mx, __shfl_xor(mx, m));

    float ex = (lane < TOPK) ? expf(sc - mx) : 0.f;
    float sum = ex;
#pragma unroll
    for (int m = 16; m >= 1; m >>= 1)
        sum += __shfl_xor(sum, m);
    float att = ex / sum;

    float acc0 = 0.f, acc1 = 0.f, acc2 = 0.f, acc3 = 0.f, acc4 = 0.f;
    const bool has5 = (lane < EMB - 256);
#pragma unroll 4
    for (int k = 0; k < TOPK; ++k) {
        const float wgt = __shfl(att, k);
        const int   id  = __shfl(nbk, k);
        const float* row = emb + (size_t)id * EMB;
        acc0 = fmaf(wgt, row[lane      ], acc0);
        acc1 = fmaf(wgt, row[lane +  64], acc1);
        acc2 = fmaf(wgt, row[lane + 128], acc2);
        acc3 = fmaf(wgt, row[lane + 192], acc3);
        if (has5) acc4 = fmaf(wgt, row[lane + 256], acc4);
    }

    float* orow = out + (size_t)tok * EMB;
    orow[lane      ] = acc0;
    orow[lane +  64] = acc1;
    orow[lane + 128] = acc2;
    orow[lane + 192] = acc3;
    if (has5) orow[lane + 256] = acc4;
}

extern "C" void kernel_launch(void* const* d_in, const int* in_sizes, int n_in,
                              void* d_out, int out_size, void* d_ws, size_t ws_size,
                              hipStream_t stream) {
    const int*   text      = (const int*)d_in[0];
    const int*   neighbors = (const int*)d_in[1];
    const float* emb       = (const float*)d_in[2];
    const float* A         = (const float*)d_in[3];
    const float* B         = (const float*)d_in[4];
    float*       out       = (float*)d_out;

    char* ws = (char*)d_ws;
    float* S0 = (float*)ws;                 // 400,000 B
    float* S1 = (float*)(ws + 400000);      // 400,000 B
    short* aT = (short*)(ws + 800000);      // 204,800 B (16B-aligned)

    prep_kernel<<<320, 256, 0, stream>>>(A, aT);
    score_kernel<<<256, 512, 0, stream>>>(emb, aT, B, S0, S1);
    attend_kernel<<<NTOK / 4, 256, 0, stream>>>(text, neighbors, emb, S0, S1, out);
}